// Round 2
// baseline (590.216 us; speedup 1.0000x reference)
//
#include <hip/hip_runtime.h>

// Problem constants (from reference setup_inputs): B=4, T=512, U=128, D=512, V=512
#define B_ 4
#define T_ 512
#define U_ 128
#define D_ 512
#define V_ 512
#define MS (B_ * T_)          // 2048 speech rows
#define MT (B_ * U_)          // 512 text rows
#define MTOT (MS + MT)        // 2560
#define LOGITS_ELEMS ((size_t)B_ * T_ * U_ * V_)   // 134217728

// GEMM tiling: 64x64 output tile, 128 threads (2 waves), 8x4 per thread,
// K-tile 32.  Grid = 40x8 = 320 blocks (was 160 @128x64 -> 96 CUs idle).
// __launch_bounds__(128,2) allows 4 blocks/CU co-resident: cross-block wave
// interleave hides each block's barrier drains and LDS-pipe bursts.
// LDS holds TRANSPOSED tiles (k-major) so the inner loop is an outer product:
//   a-reads: 8 distinct 16B segments/wave (8-way broadcast) -> conflict-free
//   b-reads: 64 consecutive floats/wave (2 bank wraps)      -> 2-way = free
//   transpose ds_write_b32: 4-way (minor, write volume is 1/4 of reads)
#define TM 64
#define TN 64
#define TK 32
#define NTHR 128
#define NTILES (D_ / TK)      // 16
#define XSTR 68               // row stride (floats): 64 + 4, keeps 16B align
#define WSTR 68

typedef float f32x4 __attribute__((ext_vector_type(4)));

// Kernel 1: C = X * W^T for X = concat(speech [2048,512], text [512,512]).
// Speech rows -> S (no bias), text rows -> Tx (+bias).
// MS % TM == 0, so each block is purely speech or purely text.
__global__ __launch_bounds__(NTHR, 2) void gemm_joint(
    const float* __restrict__ speech, const float* __restrict__ text,
    const float* __restrict__ W, const float* __restrict__ bias,
    float* __restrict__ S, float* __restrict__ Tx)
{
    __shared__ float Xt[TK][XSTR];   // Xt[k][m]
    __shared__ float Wt[TK][WSTR];   // Wt[k][n]

    const int tid = threadIdx.x;
    const int m0 = blockIdx.x * TM;
    const int n0 = blockIdx.y * TN;
    const int tx = tid & 15;         // n: 16 groups of 4 cols
    const int ty = tid >> 4;         // m: 8 groups of 8 rows

    const float* xbase = (m0 < MS) ? (speech + (size_t)m0 * D_)
                                   : (text + (size_t)(m0 - MS) * D_);

    float acc[8][4] = {};
    float4 xr[4], wr[4];

    // ---- prologue: load + transpose-store K-tile 0 ----
    #pragma unroll
    for (int i = 0; i < 4; ++i) {
        const int q = tid + NTHR * i;                 // 0..511 float4s of tile
        const int r = q >> 3, c4 = (q & 7) << 2;
        xr[i] = *(const float4*)(xbase + (size_t)r * D_ + c4);
        wr[i] = *(const float4*)(W + (size_t)(n0 + r) * D_ + c4);
    }
    #pragma unroll
    for (int i = 0; i < 4; ++i) {
        const int q = tid + NTHR * i;
        const int r = q >> 3, c = (q & 7) << 2;
        Xt[c + 0][r] = xr[i].x; Xt[c + 1][r] = xr[i].y;
        Xt[c + 2][r] = xr[i].z; Xt[c + 3][r] = xr[i].w;
        Wt[c + 0][r] = wr[i].x; Wt[c + 1][r] = wr[i].y;
        Wt[c + 2][r] = wr[i].z; Wt[c + 3][r] = wr[i].w;
    }
    __syncthreads();

    for (int t = 0; t < NTILES; ++t) {
        // register-prefetch the next K-tile across the compute phase
        if (t + 1 < NTILES) {
            const int kn = (t + 1) * TK;
            #pragma unroll
            for (int i = 0; i < 4; ++i) {
                const int q = tid + NTHR * i;
                const int r = q >> 3, c4 = (q & 7) << 2;
                xr[i] = *(const float4*)(xbase + (size_t)r * D_ + kn + c4);
                wr[i] = *(const float4*)(W + (size_t)(n0 + r) * D_ + kn + c4);
            }
        }

        // outer-product compute over the 32 k of this tile
        #pragma unroll 8
        for (int k = 0; k < TK; ++k) {
            const float4 a0 = *(const float4*)&Xt[k][ty * 8];
            const float4 a1 = *(const float4*)&Xt[k][ty * 8 + 4];
            const float4 b0 = *(const float4*)&Wt[k][tx * 4];
            const float av[8] = {a0.x, a0.y, a0.z, a0.w, a1.x, a1.y, a1.z, a1.w};
            const float bv[4] = {b0.x, b0.y, b0.z, b0.w};
            #pragma unroll
            for (int i = 0; i < 8; ++i)
                #pragma unroll
                for (int j = 0; j < 4; ++j)
                    acc[i][j] += av[i] * bv[j];
        }

        if (t + 1 < NTILES) {
            __syncthreads();   // all reads of old tile done
            #pragma unroll
            for (int i = 0; i < 4; ++i) {
                const int q = tid + NTHR * i;
                const int r = q >> 3, c = (q & 7) << 2;
                Xt[c + 0][r] = xr[i].x; Xt[c + 1][r] = xr[i].y;
                Xt[c + 2][r] = xr[i].z; Xt[c + 3][r] = xr[i].w;
                Wt[c + 0][r] = wr[i].x; Wt[c + 1][r] = wr[i].y;
                Wt[c + 2][r] = wr[i].z; Wt[c + 3][r] = wr[i].w;
            }
            __syncthreads();   // new tile visible
        }
    }

    // ---- epilogue: float4 stores; fold bias into the text rows (Tx) ----
    const int vbase = n0 + tx * 4;
    #pragma unroll
    for (int i = 0; i < 8; ++i) {
        const int m = m0 + ty * 8 + i;
        float4 o;
        o.x = acc[i][0]; o.y = acc[i][1]; o.z = acc[i][2]; o.w = acc[i][3];
        if (m < MS) {
            *(float4*)(S + (size_t)m * V_ + vbase) = o;
        } else {
            o.x += bias[vbase + 0];
            o.y += bias[vbase + 1];
            o.z += bias[vbase + 2];
            o.w += bias[vbase + 3];
            *(float4*)(Tx + (size_t)(m - MS) * V_ + vbase) = o;
        }
    }
}

// Kernel 2: out[b,t,u,v] = S[b*T+t, v] + Tx[b*U+u, v]   (bias already in Tx)
// One block per (b,t): writes a contiguous 256KB region, float4-coalesced.
// Plain stores (NT reverted: fillBuffer reaches 6.2 TB/s with write-through;
// NT-store throughput on gfx950 is unverified and is the one delta vs that
// reference).  Lens-append folded into block 0.
__global__ __launch_bounds__(256, 8) void bcast_add(
    const float* __restrict__ S, const float* __restrict__ Tx,
    const int* __restrict__ sl, const int* __restrict__ tl,
    float* __restrict__ out)
{
    const int V4 = V_ / 4;                  // 128
    const int bt = blockIdx.x;              // 0..2047
    const int b  = bt >> 9;                 // bt / T_
    const int tid = threadIdx.x;

    if (bt == 0 && tid < 2 * B_) {
        out[LOGITS_ELEMS + tid] = (tid < B_) ? (float)sl[tid]
                                             : (float)tl[tid - B_];
    }

    const f32x4* S4 = (const f32x4*)S + (size_t)bt * V4;
    const f32x4* T4 = (const f32x4*)Tx + (size_t)b * U_ * V4;
    f32x4* O4 = (f32x4*)out + (size_t)bt * U_ * V4;

    // idx % 128 == tid % 128 for every iteration -> S row element is loop-invariant
    const f32x4 sv = S4[tid & (V4 - 1)];

    #pragma unroll 8
    for (int idx = tid; idx < U_ * V4; idx += 256) {
        const f32x4 tv = T4[idx];
        O4[idx] = sv + tv;
    }
}

extern "C" void kernel_launch(void* const* d_in, const int* in_sizes, int n_in,
                              void* d_out, int out_size, void* d_ws, size_t ws_size,
                              hipStream_t stream) {
    const float* speech = (const float*)d_in[0];
    const float* text   = (const float*)d_in[1];
    const float* W      = (const float*)d_in[2];
    const float* bias   = (const float*)d_in[3];
    const int*   sl     = (const int*)d_in[4];
    const int*   tl     = (const int*)d_in[5];
    float* out = (float*)d_out;

    float* S  = (float*)d_ws;                 // [2048, 512]  (4 MB)
    float* Tx = S + (size_t)MS * V_;          // [512, 512]   (1 MB)

    dim3 g1(MTOT / TM, V_ / TN);              // 40 x 8 = 320 blocks
    gemm_joint<<<g1, NTHR, 0, stream>>>(speech, text, W, bias, S, Tx);

    bcast_add<<<MS, 256, 0, stream>>>(S, Tx, sl, tl, out);   // 2048 blocks
}

// Round 3
// 560.951 us; speedup vs baseline: 1.0522x; 1.0522x over previous
//
#include <hip/hip_runtime.h>

// Problem constants (from reference setup_inputs): B=4, T=512, U=128, D=512, V=512
#define B_ 4
#define T_ 512
#define U_ 128
#define D_ 512
#define V_ 512
#define MS (B_ * T_)          // 2048 speech rows
#define MT (B_ * U_)          // 512 text rows
#define MTOT (MS + MT)        // 2560
#define LOGITS_ELEMS ((size_t)B_ * T_ * U_ * V_)   // 134217728

// GEMM tiling: 128x64 output tile, 256 threads, 8x4 per thread, K-tile 32
// (identical inner structure to the proven 574us version).  NEW: K-split x2
// via blockIdx.z -> grid 20x8x2 = 320 blocks (was 160: ~96 of 256 CUs idle).
// Each z-half accumulates over D/2=256 and writes its own partial buffers;
// bcast_add sums the two partials (extra read traffic is L2-resident noise).
// LDS holds TRANSPOSED tiles (k-major) so the inner loop is an outer product:
//   a-reads: broadcast across 16B segments -> conflict-free
//   b-reads: 64 consecutive floats/wave    -> 2-way = free
#define TM 128
#define TN 64
#define TK 32
#define XSTR 132              // Xt row stride (floats): 128 + 4, keeps 16B align
#define WSTR 68               // Wt row stride (floats): 64 + 4

// Partial-region layout (floats): [S (MS*V) | Tx (MT*V)] repeated per z.
#define S_ELEMS ((size_t)MS * V_)          // 1048576
#define TX_ELEMS ((size_t)MT * V_)         // 262144
#define PSTRIDE (S_ELEMS + TX_ELEMS)       // 1310720 floats per partial region

typedef float f32x4 __attribute__((ext_vector_type(4)));

// Kernel 1: partial C = X * W[:, kbase:kbase+ktiles*TK]^T slice,
// X = concat(speech [2048,512], text [512,512]).
// Speech rows -> S partial, text rows -> Tx partial (+bias only when kbase==0).
__global__ __launch_bounds__(256, 2) void gemm_joint(
    const float* __restrict__ speech, const float* __restrict__ text,
    const float* __restrict__ W, const float* __restrict__ bias,
    float* __restrict__ S, float* __restrict__ Tx, int ktiles)
{
    __shared__ float Xt[TK][XSTR];   // Xt[k][m]
    __shared__ float Wt[TK][WSTR];   // Wt[k][n]

    const int tid = threadIdx.x;
    const int m0 = blockIdx.x * TM;
    const int n0 = blockIdx.y * TN;
    const int z  = blockIdx.z;
    const int kbase = z * ktiles * TK;
    const int tx = tid & 15;         // n: 16 groups of 4 cols
    const int ty = tid >> 4;         // m: 16 groups of 8 rows

    S  += (size_t)z * PSTRIDE;
    Tx += (size_t)z * PSTRIDE;

    const float* xbase = (m0 < MS) ? (speech + (size_t)m0 * D_)
                                   : (text + (size_t)(m0 - MS) * D_);

    float acc[8][4] = {};
    float4 xr[4], wr[2];

    // ---- prologue: load + transpose-store K-tile 0 of this z-half ----
    #pragma unroll
    for (int i = 0; i < 4; ++i) {
        const int q = tid + 256 * i;                  // 0..1023 float4s of X tile
        xr[i] = *(const float4*)(xbase + (size_t)(q >> 3) * D_ + kbase + ((q & 7) << 2));
    }
    #pragma unroll
    for (int i = 0; i < 2; ++i) {
        const int q = tid + 256 * i;                  // 0..511 float4s of W tile
        wr[i] = *(const float4*)(W + (size_t)(n0 + (q >> 3)) * D_ + kbase + ((q & 7) << 2));
    }
    #pragma unroll
    for (int i = 0; i < 4; ++i) {
        const int q = tid + 256 * i;
        const int r = q >> 3, c = (q & 7) << 2;
        Xt[c + 0][r] = xr[i].x; Xt[c + 1][r] = xr[i].y;
        Xt[c + 2][r] = xr[i].z; Xt[c + 3][r] = xr[i].w;
    }
    #pragma unroll
    for (int i = 0; i < 2; ++i) {
        const int q = tid + 256 * i;
        const int r = q >> 3, c = (q & 7) << 2;
        Wt[c + 0][r] = wr[i].x; Wt[c + 1][r] = wr[i].y;
        Wt[c + 2][r] = wr[i].z; Wt[c + 3][r] = wr[i].w;
    }
    __syncthreads();

    for (int t = 0; t < ktiles; ++t) {
        // register-prefetch the next K-tile across the compute phase
        if (t + 1 < ktiles) {
            const int kn = kbase + (t + 1) * TK;
            #pragma unroll
            for (int i = 0; i < 4; ++i) {
                const int q = tid + 256 * i;
                xr[i] = *(const float4*)(xbase + (size_t)(q >> 3) * D_ + kn + ((q & 7) << 2));
            }
            #pragma unroll
            for (int i = 0; i < 2; ++i) {
                const int q = tid + 256 * i;
                wr[i] = *(const float4*)(W + (size_t)(n0 + (q >> 3)) * D_ + kn + ((q & 7) << 2));
            }
        }

        // outer-product compute over the 32 k of this tile
        #pragma unroll 8
        for (int k = 0; k < TK; ++k) {
            const float4 a0 = *(const float4*)&Xt[k][ty * 8];
            const float4 a1 = *(const float4*)&Xt[k][ty * 8 + 4];
            const float4 b0 = *(const float4*)&Wt[k][tx * 4];
            const float av[8] = {a0.x, a0.y, a0.z, a0.w, a1.x, a1.y, a1.z, a1.w};
            const float bv[4] = {b0.x, b0.y, b0.z, b0.w};
            #pragma unroll
            for (int i = 0; i < 8; ++i)
                #pragma unroll
                for (int j = 0; j < 4; ++j)
                    acc[i][j] += av[i] * bv[j];
        }

        if (t + 1 < ktiles) {
            __syncthreads();   // all reads of old tile done
            #pragma unroll
            for (int i = 0; i < 4; ++i) {
                const int q = tid + 256 * i;
                const int r = q >> 3, c = (q & 7) << 2;
                Xt[c + 0][r] = xr[i].x; Xt[c + 1][r] = xr[i].y;
                Xt[c + 2][r] = xr[i].z; Xt[c + 3][r] = xr[i].w;
            }
            #pragma unroll
            for (int i = 0; i < 2; ++i) {
                const int q = tid + 256 * i;
                const int r = q >> 3, c = (q & 7) << 2;
                Wt[c + 0][r] = wr[i].x; Wt[c + 1][r] = wr[i].y;
                Wt[c + 2][r] = wr[i].z; Wt[c + 3][r] = wr[i].w;
            }
            __syncthreads();   // new tile visible
        }
    }

    // ---- epilogue: float4 stores; fold bias into text rows of the z=0 partial ----
    const int vbase = n0 + tx * 4;
    #pragma unroll
    for (int i = 0; i < 8; ++i) {
        const int m = m0 + ty * 8 + i;
        float4 o;
        o.x = acc[i][0]; o.y = acc[i][1]; o.z = acc[i][2]; o.w = acc[i][3];
        if (m < MS) {
            *(float4*)(S + (size_t)m * V_ + vbase) = o;
        } else {
            if (kbase == 0) {
                o.x += bias[vbase + 0];
                o.y += bias[vbase + 1];
                o.z += bias[vbase + 2];
                o.w += bias[vbase + 3];
            }
            *(float4*)(Tx + (size_t)(m - MS) * V_ + vbase) = o;
        }
    }
}

// Kernel 2: out[b,t,u,v] = S[b*T+t, v] + Tx[b*U+u, v]   (bias already in Tx)
// One block per (b,t): writes a contiguous 256KB region. Non-temporal stores
// (proven in the 574us version) keep the 537MB stream from thrashing L2.
// SPLIT variant sums the two K-partials. Lens-append folded into block 0.
template <bool SPLIT>
__global__ __launch_bounds__(256, 8) void bcast_add(
    const float* __restrict__ S, const float* __restrict__ Tx,
    const int* __restrict__ sl, const int* __restrict__ tl,
    float* __restrict__ out)
{
    const int V4 = V_ / 4;                  // 128
    const int bt = blockIdx.x;              // 0..2047
    const int b  = bt >> 9;                 // bt / T_
    const int tid = threadIdx.x;

    if (bt == 0 && tid < 2 * B_) {
        out[LOGITS_ELEMS + tid] = (tid < B_) ? (float)sl[tid]
                                             : (float)tl[tid - B_];
    }

    const f32x4* S4 = (const f32x4*)S + (size_t)bt * V4;
    const f32x4* T4 = (const f32x4*)Tx + (size_t)b * U_ * V4;
    f32x4* O4 = (f32x4*)out + (size_t)bt * U_ * V4;

    // idx % 128 == tid % 128 for every iteration -> S row element is loop-invariant
    f32x4 sv = S4[tid & (V4 - 1)];
    if (SPLIT) sv += S4[(PSTRIDE / 4) + (tid & (V4 - 1))];

    #pragma unroll 8
    for (int idx = tid; idx < U_ * V4; idx += 256) {
        f32x4 tv = T4[idx];
        if (SPLIT) tv += T4[(PSTRIDE / 4) + idx];
        __builtin_nontemporal_store(sv + tv, &O4[idx]);
    }
}

extern "C" void kernel_launch(void* const* d_in, const int* in_sizes, int n_in,
                              void* d_out, int out_size, void* d_ws, size_t ws_size,
                              hipStream_t stream) {
    const float* speech = (const float*)d_in[0];
    const float* text   = (const float*)d_in[1];
    const float* W      = (const float*)d_in[2];
    const float* bias   = (const float*)d_in[3];
    const int*   sl     = (const int*)d_in[4];
    const int*   tl     = (const int*)d_in[5];
    float* out = (float*)d_out;

    float* S  = (float*)d_ws;                 // partial 0: [S | Tx]
    float* Tx = S + S_ELEMS;                  // partial 1 lives at +PSTRIDE

    const bool split = ws_size >= 2 * PSTRIDE * sizeof(float);

    if (split) {
        dim3 g1(MTOT / TM, V_ / TN, 2);       // 20 x 8 x 2 = 320 blocks
        gemm_joint<<<g1, 256, 0, stream>>>(speech, text, W, bias, S, Tx, (D_ / TK) / 2);
        bcast_add<true><<<MS, 256, 0, stream>>>(S, Tx, sl, tl, out);
    } else {
        dim3 g1(MTOT / TM, V_ / TN, 1);       // fallback: unsplit (574us config)
        gemm_joint<<<g1, 256, 0, stream>>>(speech, text, W, bias, S, Tx, D_ / TK);
        bcast_add<false><<<MS, 256, 0, stream>>>(S, Tx, sl, tl, out);
    }
}